// Round 2
// baseline (255.071 us; speedup 1.0000x reference)
//
#include <hip/hip_runtime.h>
#include <hip/hip_bf16.h>
#include <stdint.h>

typedef unsigned short ushort_t;
typedef __attribute__((ext_vector_type(8))) __bf16 bf16x8;
typedef __attribute__((ext_vector_type(4))) float f32x4;

typedef const __attribute__((address_space(1))) uint32_t* gptr_t;
typedef __attribute__((address_space(3))) uint32_t* lptr_t;

__device__ __forceinline__ ushort_t f2bf(float f) {
  union { float f; uint32_t u; } x; x.f = f;
  uint32_t u = x.u;
  uint32_t r = (u + 0x7fffu + ((u >> 16) & 1u)) >> 16;
  return (ushort_t)r;
}

__device__ __forceinline__ void gload_lds16(const void* g, void* l) {
  __builtin_amdgcn_global_load_lds((gptr_t)g, (lptr_t)l, 16, 0, 0);
}

// ---------------- cast x (fp32 -> bf16) ----------------
__global__ void cast_x(const float* __restrict__ in, ushort_t* __restrict__ out, int n) {
  const int idx = (blockIdx.x * 256 + threadIdx.x) * 4;
  if (idx < n) {
    const float4 v = *(const float4*)(in + idx);
    ushort4 o;
    o.x = f2bf(v.x); o.y = f2bf(v.y); o.z = f2bf(v.z); o.w = f2bf(v.w);
    *(ushort4*)(out + idx) = o;
  }
}

// ---------------- transpose + cast weights: in[K][N] fp32 -> out[N][K] bf16 ----------------
__global__ void transpose_cast(const float* __restrict__ in, ushort_t* __restrict__ out, int K, int N) {
  __shared__ ushort_t t[32][33];
  const int n0 = blockIdx.x * 32, k0 = blockIdx.y * 32;
  const int c = threadIdx.x & 31, r0 = threadIdx.x >> 5;
#pragma unroll
  for (int i = 0; i < 4; ++i) {
    const int r = r0 + i * 8;
    t[r][c] = f2bf(in[(size_t)(k0 + r) * N + n0 + c]);
  }
  __syncthreads();
#pragma unroll
  for (int i = 0; i < 4; ++i) {
    const int r = r0 + i * 8;
    out[(size_t)(n0 + r) * K + k0 + c] = t[c][r];
  }
}

// ---------------- GEMM: C[M,N] = A[M,K] * Bt[N,K]^T + bias ----------------
// MODE 1: fp32 out to Cf.
// MODE 2: bf16 out scattered: Q,K -> [BH][S][D] (Q pre-scaled), V -> [BH][D][S].
template<int MODE>
__global__ __launch_bounds__(256, 2) void gemm_bt(
    const ushort_t* __restrict__ A, const ushort_t* __restrict__ Bt,
    const float* __restrict__ bias,
    ushort_t* __restrict__ Cq, ushort_t* __restrict__ Ck, ushort_t* __restrict__ Cv,
    float* __restrict__ Cf,
    int M, int N, int K, float qscale)
{
  __shared__ ushort_t As[128 * 64];
  __shared__ ushort_t Bs[128 * 64];
  const int tid = threadIdx.x;
  const int w = tid >> 6, l = tid & 63;
  const int bm = blockIdx.y * 128, bn = blockIdx.x * 128;
  const int lr = l >> 3, lp = l & 7;
  const int l16 = l & 15, lhi = l >> 4;
  const int wm = (w >> 1) * 64, wn = (w & 1) * 64;

  f32x4 acc[4][4] = {};

  for (int kt = 0; kt < K; kt += 64) {
#pragma unroll
    for (int i = 0; i < 4; ++i) {
      const int ci = i * 4 + w;
      const int row = ci * 8 + lr;
      const int sc = (lp ^ (row & 7)) * 8;
      gload_lds16(A + (size_t)(bm + row) * K + kt + sc, &As[ci * 512]);
      gload_lds16(Bt + (size_t)(bn + row) * K + kt + sc, &Bs[ci * 512]);
    }
    __syncthreads();

    bf16x8 af[4][2], bfr[4][2];
#pragma unroll
    for (int mf = 0; mf < 4; ++mf) {
      const int row = wm + mf * 16 + l16;
#pragma unroll
      for (int kf = 0; kf < 2; ++kf) {
        const int ch = (lhi + kf * 4) ^ (row & 7);
        af[mf][kf] = *(const bf16x8*)((const char*)&As[row * 64] + ch * 16);
      }
    }
#pragma unroll
    for (int nf = 0; nf < 4; ++nf) {
      const int row = wn + nf * 16 + l16;
#pragma unroll
      for (int kf = 0; kf < 2; ++kf) {
        const int ch = (lhi + kf * 4) ^ (row & 7);
        bfr[nf][kf] = *(const bf16x8*)((const char*)&Bs[row * 64] + ch * 16);
      }
    }
#pragma unroll
    for (int kf = 0; kf < 2; ++kf)
#pragma unroll
      for (int mf = 0; mf < 4; ++mf)
#pragma unroll
        for (int nf = 0; nf < 4; ++nf)
          acc[mf][nf] = __builtin_amdgcn_mfma_f32_16x16x32_bf16(
              af[mf][kf], bfr[nf][kf], acc[mf][nf], 0, 0, 0);
    __syncthreads();
  }

#pragma unroll
  for (int mf = 0; mf < 4; ++mf) {
#pragma unroll
    for (int nf = 0; nf < 4; ++nf) {
      const int col = bn + wn + nf * 16 + l16;
      const float bv = bias[col];
#pragma unroll
      for (int r = 0; r < 4; ++r) {
        const int row = bm + wm + mf * 16 + lhi * 4 + r;
        float v = acc[mf][nf][r] + bv;
        if constexpr (MODE == 1) {
          Cf[(size_t)row * N + col] = v;
        } else {
          const int region = col >> 10;
          const int hcol = col & 1023;
          const int b_ = row >> 10, s_ = row & 1023;
          const int h_ = hcol >> 6, d_ = hcol & 63;
          if (region == 2) {
            // V: write transposed [BH][D][S]
            Cv[((size_t)(b_ * 16 + h_) * 64 + d_) * 1024 + s_] = f2bf(v);
          } else {
            ushort_t* base = (region == 0) ? Cq : Ck;
            if (region == 0) v *= qscale;
            base[((size_t)(b_ * 16 + h_) * 1024 + s_) * 64 + d_] = f2bf(v);
          }
        }
      }
    }
  }
}

// ---------------- causal flash attention ----------------
// Q pre-scaled by 0.125*log2(e); Q,K in [BH][S][D]; V in [BH][D][S]; out bf16 [B,S,E]
__global__ __launch_bounds__(256, 2) void attn_kernel(
    const ushort_t* __restrict__ Q, const ushort_t* __restrict__ Kk,
    const ushort_t* __restrict__ Vt, ushort_t* __restrict__ O)
{
  __shared__ ushort_t Ql[128 * 64];
  __shared__ ushort_t Kl[64 * 64];
  __shared__ ushort_t Vl[64 * 64];
  __shared__ ushort_t Pl[4][32 * 64];
  const int tid = threadIdx.x;
  const int w = tid >> 6, l = tid & 63;
  const int l16 = l & 15, lhi = l >> 4;
  const int lr = l >> 3, lp = l & 7;
  const int qt = (int)gridDim.x - 1 - (int)blockIdx.x;  // heavy tiles first
  const int bh = blockIdx.y;
  const int q0 = qt * 128;
  const size_t hb = (size_t)bh * (1024 * 64);

#pragma unroll
  for (int i = 0; i < 4; ++i) {
    const int ci = i * 4 + w;
    const int row = ci * 8 + lr;
    const int sc = (lp ^ (row & 7)) * 8;
    gload_lds16(Q + hb + (size_t)(q0 + row) * 64 + sc, &Ql[ci * 512]);
  }
  __syncthreads();

  bf16x8 qf[2][2];
#pragma unroll
  for (int mf = 0; mf < 2; ++mf) {
    const int row = w * 32 + mf * 16 + l16;
#pragma unroll
    for (int kf = 0; kf < 2; ++kf) {
      const int ch = (lhi + kf * 4) ^ (row & 7);
      qf[mf][kf] = *(const bf16x8*)((const char*)&Ql[row * 64] + ch * 16);
    }
  }

  f32x4 o[2][4] = {};
  float m_run[2][4], l_run[2][4];
#pragma unroll
  for (int mf = 0; mf < 2; ++mf)
#pragma unroll
    for (int r = 0; r < 4; ++r) { m_run[mf][r] = -1e30f; l_run[mf][r] = 0.0f; }

  const int nt = 2 * qt + 2;
  for (int t = 0; t < nt; ++t) {
    const int kv0 = t * 64;
#pragma unroll
    for (int i = 0; i < 2; ++i) {
      const int ci = i * 4 + w;
      const int row = ci * 8 + lr;
      const int sc = (lp ^ (row & 7)) * 8;
      gload_lds16(Kk + hb + (size_t)(kv0 + row) * 64 + sc, &Kl[ci * 512]);
      gload_lds16(Vt + hb + (size_t)row * 1024 + kv0 + sc, &Vl[ci * 512]);
    }
    __syncthreads();

    if (kv0 <= q0 + w * 32 + 31) {  // wave-level causal tile skip
      f32x4 s[2][4] = {};
#pragma unroll
      for (int nf = 0; nf < 4; ++nf) {
        const int row = nf * 16 + l16;
#pragma unroll
        for (int kf = 0; kf < 2; ++kf) {
          const int ch = (lhi + kf * 4) ^ (row & 7);
          const bf16x8 kb = *(const bf16x8*)((const char*)&Kl[row * 64] + ch * 16);
#pragma unroll
          for (int mf = 0; mf < 2; ++mf)
            s[mf][nf] = __builtin_amdgcn_mfma_f32_16x16x32_bf16(qf[mf][kf], kb, s[mf][nf], 0, 0, 0);
        }
      }

      if (kv0 + 63 > q0 + w * 32) {  // diagonal tile: elementwise causal mask
#pragma unroll
        for (int mf = 0; mf < 2; ++mf)
#pragma unroll
          for (int nf = 0; nf < 4; ++nf)
#pragma unroll
            for (int r = 0; r < 4; ++r) {
              const int qrow = q0 + w * 32 + mf * 16 + lhi * 4 + r;
              const int kvc = kv0 + nf * 16 + l16;
              if (kvc > qrow) s[mf][nf][r] = -1e30f;
            }
      }

#pragma unroll
      for (int mf = 0; mf < 2; ++mf) {
#pragma unroll
        for (int r = 0; r < 4; ++r) {
          float cand = fmaxf(fmaxf(s[mf][0][r], s[mf][1][r]), fmaxf(s[mf][2][r], s[mf][3][r]));
#pragma unroll
          for (int msk = 1; msk < 16; msk <<= 1)
            cand = fmaxf(cand, __shfl_xor(cand, msk));
          const float mold = m_run[mf][r];
          const float mnew = fmaxf(mold, cand);
          const float corr = exp2f(mold - mnew);
          float psum = 0.0f;
#pragma unroll
          for (int nf = 0; nf < 4; ++nf) {
            const float p = exp2f(s[mf][nf][r] - mnew);
            s[mf][nf][r] = p;
            psum += p;
          }
#pragma unroll
          for (int msk = 1; msk < 16; msk <<= 1)
            psum += __shfl_xor(psum, msk);
          l_run[mf][r] = l_run[mf][r] * corr + psum;
          m_run[mf][r] = mnew;
#pragma unroll
          for (int nf = 0; nf < 4; ++nf) o[mf][nf][r] *= corr;
        }
      }

      // P -> LDS (bf16, swizzled), private per wave
#pragma unroll
      for (int mf = 0; mf < 2; ++mf)
#pragma unroll
        for (int nf = 0; nf < 4; ++nf)
#pragma unroll
          for (int r = 0; r < 4; ++r) {
            const int prow = mf * 16 + lhi * 4 + r;
            const int pcol = nf * 16 + l16;
            const int boff = (pcol * 2) ^ ((prow & 7) << 4);
            *(ushort_t*)((char*)&Pl[w][prow * 64] + boff) = f2bf(s[mf][nf][r]);
          }

      // PV
#pragma unroll
      for (int kf = 0; kf < 2; ++kf) {
        bf16x8 pa[2];
#pragma unroll
        for (int mf = 0; mf < 2; ++mf) {
          const int row = mf * 16 + l16;
          const int ch = (lhi + kf * 4) ^ (row & 7);
          pa[mf] = *(const bf16x8*)((const char*)&Pl[w][row * 64] + ch * 16);
        }
#pragma unroll
        for (int nf = 0; nf < 4; ++nf) {
          const int vrow = nf * 16 + l16;
          const int ch = (lhi + kf * 4) ^ (vrow & 7);
          const bf16x8 vb = *(const bf16x8*)((const char*)&Vl[vrow * 64] + ch * 16);
#pragma unroll
          for (int mf = 0; mf < 2; ++mf)
            o[mf][nf] = __builtin_amdgcn_mfma_f32_16x16x32_bf16(pa[mf], vb, o[mf][nf], 0, 0, 0);
        }
      }
    }
    __syncthreads();
  }

  const int b_ = bh >> 4, h_ = bh & 15;
#pragma unroll
  for (int mf = 0; mf < 2; ++mf) {
#pragma unroll
    for (int r = 0; r < 4; ++r) {
      const float inv = 1.0f / l_run[mf][r];
      const int qrow = q0 + w * 32 + mf * 16 + lhi * 4 + r;
      const size_t rb = ((size_t)(b_ * 1024 + qrow)) * 1024 + h_ * 64;
#pragma unroll
      for (int nf = 0; nf < 4; ++nf)
        O[rb + nf * 16 + l16] = f2bf(o[mf][nf][r] * inv);
    }
  }
}

extern "C" void kernel_launch(void* const* d_in, const int* in_sizes, int n_in,
                              void* d_out, int out_size, void* d_ws, size_t ws_size,
                              hipStream_t stream) {
  const float* x      = (const float*)d_in[0];
  const float* W_attn = (const float*)d_in[1];
  const float* b_attn = (const float*)d_in[2];
  const float* W_proj = (const float*)d_in[3];
  const float* b_proj = (const float*)d_in[4];
  float* out = (float*)d_out;

  const int M = 8192;       // B*S
  const int E = 1024, N3 = 3072;
  const size_t T = (size_t)M * E;  // 8.4M elements per [B,S,E]-sized bf16 tensor

  char* p = (char*)d_ws;
  ushort_t* xb  = (ushort_t*)p; p += T * 2;              // x bf16; reused as attn_out
  ushort_t* Wab = (ushort_t*)p; p += (size_t)N3 * E * 2; // W_attn^T bf16 [3072][1024]
  ushort_t* Wpb = (ushort_t*)p; p += (size_t)E * E * 2;  // W_proj^T bf16 [1024][1024]
  ushort_t* Qb  = (ushort_t*)p; p += T * 2;              // [BH][S][D]
  ushort_t* Kb  = (ushort_t*)p; p += T * 2;              // [BH][S][D]
  ushort_t* Vtb = (ushort_t*)p; p += T * 2;              // [BH][D][S]

  const float qscale = 0.125f * 1.4426950408889634f;     // 1/sqrt(D) * log2(e)

  cast_x<<<dim3((int)(T / 1024)), dim3(256), 0, stream>>>(x, xb, (int)T);
  transpose_cast<<<dim3(N3 / 32, E / 32), dim3(256), 0, stream>>>(W_attn, Wab, E, N3);
  transpose_cast<<<dim3(E / 32, E / 32), dim3(256), 0, stream>>>(W_proj, Wpb, E, E);
  gemm_bt<2><<<dim3(N3 / 128, M / 128), dim3(256), 0, stream>>>(
      xb, Wab, b_attn, Qb, Kb, Vtb, nullptr, M, N3, E, qscale);
  attn_kernel<<<dim3(8, 128), dim3(256), 0, stream>>>(Qb, Kb, Vtb, xb);
  gemm_bt<1><<<dim3(E / 128, M / 128), dim3(256), 0, stream>>>(
      xb, Wpb, b_proj, nullptr, nullptr, nullptr, out, M, E, E, 1.0f);
}

// Round 3
// 228.009 us; speedup vs baseline: 1.1187x; 1.1187x over previous
//
#include <hip/hip_runtime.h>
#include <hip/hip_bf16.h>
#include <stdint.h>

typedef unsigned short ushort_t;
typedef __attribute__((ext_vector_type(8))) __bf16 bf16x8;
typedef __attribute__((ext_vector_type(4))) float f32x4;

typedef const __attribute__((address_space(1))) uint32_t* gptr_t;
typedef __attribute__((address_space(3))) uint32_t* lptr_t;

__device__ __forceinline__ ushort_t f2bf(float f) {
  union { float f; uint32_t u; } x; x.f = f;
  uint32_t u = x.u;
  uint32_t r = (u + 0x7fffu + ((u >> 16) & 1u)) >> 16;
  return (ushort_t)r;
}

__device__ __forceinline__ uint32_t cvt_pk_bf16(float lo, float hi) {
  uint32_t r;
  asm("v_cvt_pk_bf16_f32 %0, %1, %2" : "=v"(r) : "v"(lo), "v"(hi));
  return r;
}

__device__ __forceinline__ void gload_lds16(const void* g, void* l) {
  __builtin_amdgcn_global_load_lds((gptr_t)g, (lptr_t)l, 16, 0, 0);
}

// ---------------- cast x (fp32 -> bf16) ----------------
__global__ void cast_x(const float* __restrict__ in, ushort_t* __restrict__ out, int n) {
  const int idx = (blockIdx.x * 256 + threadIdx.x) * 4;
  if (idx < n) {
    const float4 v = *(const float4*)(in + idx);
    ushort4 o;
    o.x = f2bf(v.x); o.y = f2bf(v.y); o.z = f2bf(v.z); o.w = f2bf(v.w);
    *(ushort4*)(out + idx) = o;
  }
}

// ---------------- transpose + cast weights: in[K][N] fp32 -> out[N][K] bf16 ----------------
__global__ void transpose_cast(const float* __restrict__ in, ushort_t* __restrict__ out, int K, int N) {
  __shared__ ushort_t t[32][33];
  const int n0 = blockIdx.x * 32, k0 = blockIdx.y * 32;
  const int c = threadIdx.x & 31, r0 = threadIdx.x >> 5;
#pragma unroll
  for (int i = 0; i < 4; ++i) {
    const int r = r0 + i * 8;
    t[r][c] = f2bf(in[(size_t)(k0 + r) * N + n0 + c]);
  }
  __syncthreads();
#pragma unroll
  for (int i = 0; i < 4; ++i) {
    const int r = r0 + i * 8;
    out[(size_t)(n0 + r) * K + k0 + c] = t[c][r];
  }
}

// ---------------- GEMM: C[M,N] = A[M,K] * Bt[N,K]^T + bias ----------------
// MODE 1: fp32 out to Cf.
// MODE 2: bf16 out scattered: Q,K -> [BH][S][D] (Q pre-scaled), V -> [BH][D][S].
template<int MODE>
__global__ __launch_bounds__(256, 2) void gemm_bt(
    const ushort_t* __restrict__ A, const ushort_t* __restrict__ Bt,
    const float* __restrict__ bias,
    ushort_t* __restrict__ Cq, ushort_t* __restrict__ Ck, ushort_t* __restrict__ Cv,
    float* __restrict__ Cf,
    int M, int N, int K, float qscale)
{
  __shared__ ushort_t As[128 * 64];
  __shared__ ushort_t Bs[128 * 64];
  const int tid = threadIdx.x;
  const int w = tid >> 6, l = tid & 63;
  const int bm = blockIdx.y * 128, bn = blockIdx.x * 128;
  const int lr = l >> 3, lp = l & 7;
  const int l16 = l & 15, lhi = l >> 4;
  const int wm = (w >> 1) * 64, wn = (w & 1) * 64;

  f32x4 acc[4][4] = {};

  for (int kt = 0; kt < K; kt += 64) {
#pragma unroll
    for (int i = 0; i < 4; ++i) {
      const int ci = i * 4 + w;
      const int row = ci * 8 + lr;
      const int sc = (lp ^ (row & 7)) * 8;
      gload_lds16(A + (size_t)(bm + row) * K + kt + sc, &As[ci * 512]);
      gload_lds16(Bt + (size_t)(bn + row) * K + kt + sc, &Bs[ci * 512]);
    }
    __syncthreads();

    bf16x8 af[4][2], bfr[4][2];
#pragma unroll
    for (int mf = 0; mf < 4; ++mf) {
      const int row = wm + mf * 16 + l16;
#pragma unroll
      for (int kf = 0; kf < 2; ++kf) {
        const int ch = (lhi + kf * 4) ^ (row & 7);
        af[mf][kf] = *(const bf16x8*)((const char*)&As[row * 64] + ch * 16);
      }
    }
#pragma unroll
    for (int nf = 0; nf < 4; ++nf) {
      const int row = wn + nf * 16 + l16;
#pragma unroll
      for (int kf = 0; kf < 2; ++kf) {
        const int ch = (lhi + kf * 4) ^ (row & 7);
        bfr[nf][kf] = *(const bf16x8*)((const char*)&Bs[row * 64] + ch * 16);
      }
    }
#pragma unroll
    for (int kf = 0; kf < 2; ++kf)
#pragma unroll
      for (int mf = 0; mf < 4; ++mf)
#pragma unroll
        for (int nf = 0; nf < 4; ++nf)
          acc[mf][nf] = __builtin_amdgcn_mfma_f32_16x16x32_bf16(
              af[mf][kf], bfr[nf][kf], acc[mf][nf], 0, 0, 0);
    __syncthreads();
  }

#pragma unroll
  for (int mf = 0; mf < 4; ++mf) {
#pragma unroll
    for (int nf = 0; nf < 4; ++nf) {
      const int col = bn + wn + nf * 16 + l16;
      const float bv = bias[col];
#pragma unroll
      for (int r = 0; r < 4; ++r) {
        const int row = bm + wm + mf * 16 + lhi * 4 + r;
        float v = acc[mf][nf][r] + bv;
        if constexpr (MODE == 1) {
          Cf[(size_t)row * N + col] = v;
        } else {
          const int region = col >> 10;
          const int hcol = col & 1023;
          const int b_ = row >> 10, s_ = row & 1023;
          const int h_ = hcol >> 6, d_ = hcol & 63;
          if (region == 2) {
            // V: write transposed [BH][D][S]
            Cv[((size_t)(b_ * 16 + h_) * 64 + d_) * 1024 + s_] = f2bf(v);
          } else {
            ushort_t* base = (region == 0) ? Cq : Ck;
            if (region == 0) v *= qscale;
            base[((size_t)(b_ * 16 + h_) * 1024 + s_) * 64 + d_] = f2bf(v);
          }
        }
      }
    }
  }
}

// ---------------- causal flash attention (swapped-operand, barrier-free) ----------------
// Q pre-scaled by 0.125*log2(e); Q,K in [BH][S][D]; V in [BH][D][S]; out bf16 [B,S,E].
// Computes S^T = K·Q^T per tile so each lane owns one q-column: softmax reduction is
// in-register + 2 shfl_xor. PV swapped too: O^T = V^T·P^T. No K/V/Q LDS staging, no
// __syncthreads — waves fully independent with exact causal trip counts.
__global__ __launch_bounds__(256, 3) void attn_kernel(
    const ushort_t* __restrict__ Q, const ushort_t* __restrict__ Kk,
    const ushort_t* __restrict__ Vt, ushort_t* __restrict__ O)
{
  __shared__ ushort_t Pl[4][32 * 64];  // per-wave P[q][kv], XOR-swizzled rows
  const int tid = threadIdx.x;
  const int w = tid >> 6, l = tid & 63;
  const int l16 = l & 15, lhi = l >> 4;

  // XCD swizzle: all 8 q-tiles of a head share bid%8 -> same XCD L2 (K/V stay resident).
  const int bid = blockIdx.x;
  const int bh = ((bid >> 6) << 3) | (bid & 7);   // head 0..127
  const int qt = 7 - ((bid >> 3) & 7);            // heavy q-tiles dispatch first
  const int qbase = qt * 128 + w * 32;            // this wave's 32 q-rows
  const size_t hb = (size_t)bh * (1024 * 64);

  // Q fragments (B-operand: lane holds Q[q=l16][ch=kf*32+lhi*8+j])
  bf16x8 qf[2][2];
#pragma unroll
  for (int mf = 0; mf < 2; ++mf)
#pragma unroll
    for (int kf = 0; kf < 2; ++kf)
      qf[mf][kf] = *(const bf16x8*)(Q + hb + (size_t)(qbase + mf * 16 + l16) * 64 + kf * 32 + lhi * 8);

  f32x4 o[2][4] = {};
  float m_run[2] = {-1e30f, -1e30f};
  float l_run[2] = {0.0f, 0.0f};
  char* const pbase = (char*)&Pl[w][0];

  const int nt = (qbase >> 6) + 1;
  for (int t = 0; t < nt; ++t) {
    const int kv0 = t * 64;

    // K fragments (A-operand: lane holds K[kv=nf*16+l16][ch=kf*32+lhi*8+j])
    bf16x8 kb[4][2];
#pragma unroll
    for (int nf = 0; nf < 4; ++nf)
#pragma unroll
      for (int kf = 0; kf < 2; ++kf)
        kb[nf][kf] = *(const bf16x8*)(Kk + hb + (size_t)(kv0 + nf * 16 + l16) * 64 + kf * 32 + lhi * 8);

    // S^T[kv][q] = K·Q^T
    f32x4 s[2][4] = {};
#pragma unroll
    for (int nf = 0; nf < 4; ++nf)
#pragma unroll
      for (int kf = 0; kf < 2; ++kf)
#pragma unroll
        for (int mf = 0; mf < 2; ++mf)
          s[mf][nf] = __builtin_amdgcn_mfma_f32_16x16x32_bf16(kb[nf][kf], qf[mf][kf], s[mf][nf], 0, 0, 0);

    // V^T fragments for PV (A-operand: lane holds V^T[d=nf*16+l16][kv=kv0+kf*32+lhi*8+j])
    bf16x8 vb[4][2];
#pragma unroll
    for (int nf = 0; nf < 4; ++nf)
#pragma unroll
      for (int kf = 0; kf < 2; ++kf)
        vb[nf][kf] = *(const bf16x8*)(Vt + hb + (size_t)(nf * 16 + l16) * 1024 + kv0 + kf * 32 + lhi * 8);

    if (kv0 + 63 > qbase) {  // diagonal tile: elementwise causal mask
#pragma unroll
      for (int mf = 0; mf < 2; ++mf) {
        const int q = qbase + mf * 16 + l16;
#pragma unroll
        for (int nf = 0; nf < 4; ++nf)
#pragma unroll
          for (int r = 0; r < 4; ++r) {
            const int kv = kv0 + nf * 16 + lhi * 4 + r;
            if (kv > q) s[mf][nf][r] = -1e30f;
          }
      }
    }

    // online softmax: in-register over 16 kv + 2 shfl_xor across lhi partners
#pragma unroll
    for (int mf = 0; mf < 2; ++mf) {
      float lmax = -1e30f;
#pragma unroll
      for (int nf = 0; nf < 4; ++nf)
#pragma unroll
        for (int r = 0; r < 4; ++r) lmax = fmaxf(lmax, s[mf][nf][r]);
      lmax = fmaxf(lmax, __shfl_xor(lmax, 16));
      lmax = fmaxf(lmax, __shfl_xor(lmax, 32));
      const float mnew = fmaxf(m_run[mf], lmax);
      const float corr = exp2f(m_run[mf] - mnew);
      float psum = 0.0f;
#pragma unroll
      for (int nf = 0; nf < 4; ++nf)
#pragma unroll
        for (int r = 0; r < 4; ++r) {
          const float p = exp2f(s[mf][nf][r] - mnew);
          s[mf][nf][r] = p;
          psum += p;
        }
      psum += __shfl_xor(psum, 16);
      psum += __shfl_xor(psum, 32);
      l_run[mf] = l_run[mf] * corr + psum;
      m_run[mf] = mnew;
#pragma unroll
      for (int nf = 0; nf < 4; ++nf) o[mf][nf] *= corr;

      // store P row q (bf16, swizzled): P[q][kv = nf*16+lhi*4 + 0..3]
      const int q = mf * 16 + l16;
#pragma unroll
      for (int nf = 0; nf < 4; ++nf) {
        const uint32_t u0 = cvt_pk_bf16(s[mf][nf][0], s[mf][nf][1]);
        const uint32_t u1 = cvt_pk_bf16(s[mf][nf][2], s[mf][nf][3]);
        const int off = (nf * 32 + lhi * 8) ^ ((q & 7) << 4);
        *(uint2*)(pbase + q * 128 + off) = make_uint2(u0, u1);
      }
    }

    // O^T += V^T·P^T  (wave-private LDS, compiler inserts lgkmcnt wait)
#pragma unroll
    for (int mf = 0; mf < 2; ++mf) {
      const int q = mf * 16 + l16;
#pragma unroll
      for (int kf = 0; kf < 2; ++kf) {
        const int off = (kf * 64 + lhi * 16) ^ ((q & 7) << 4);
        const bf16x8 pb = *(const bf16x8*)(pbase + q * 128 + off);
#pragma unroll
        for (int nf = 0; nf < 4; ++nf)
          o[mf][nf] = __builtin_amdgcn_mfma_f32_16x16x32_bf16(vb[nf][kf], pb, o[mf][nf], 0, 0, 0);
      }
    }
  }

  // epilogue: normalize, pack 4 bf16 (consecutive d) per store
  const int b_ = bh >> 4, h_ = bh & 15;
#pragma unroll
  for (int mf = 0; mf < 2; ++mf) {
    const float inv = 1.0f / l_run[mf];
    const int qrow = qbase + mf * 16 + l16;
    const size_t rb = ((size_t)(b_ * 1024 + qrow)) * 1024 + h_ * 64;
#pragma unroll
    for (int nf = 0; nf < 4; ++nf) {
      const uint32_t u0 = cvt_pk_bf16(o[mf][nf][0] * inv, o[mf][nf][1] * inv);
      const uint32_t u1 = cvt_pk_bf16(o[mf][nf][2] * inv, o[mf][nf][3] * inv);
      *(uint2*)(O + rb + nf * 16 + lhi * 4) = make_uint2(u0, u1);
    }
  }
}

extern "C" void kernel_launch(void* const* d_in, const int* in_sizes, int n_in,
                              void* d_out, int out_size, void* d_ws, size_t ws_size,
                              hipStream_t stream) {
  const float* x      = (const float*)d_in[0];
  const float* W_attn = (const float*)d_in[1];
  const float* b_attn = (const float*)d_in[2];
  const float* W_proj = (const float*)d_in[3];
  const float* b_proj = (const float*)d_in[4];
  float* out = (float*)d_out;

  const int M = 8192;       // B*S
  const int E = 1024, N3 = 3072;
  const size_t T = (size_t)M * E;  // 8.4M elements per [B,S,E]-sized bf16 tensor

  char* p = (char*)d_ws;
  ushort_t* xb  = (ushort_t*)p; p += T * 2;              // x bf16; reused as attn_out
  ushort_t* Wab = (ushort_t*)p; p += (size_t)N3 * E * 2; // W_attn^T bf16 [3072][1024]
  ushort_t* Wpb = (ushort_t*)p; p += (size_t)E * E * 2;  // W_proj^T bf16 [1024][1024]
  ushort_t* Qb  = (ushort_t*)p; p += T * 2;              // [BH][S][D]
  ushort_t* Kb  = (ushort_t*)p; p += T * 2;              // [BH][S][D]
  ushort_t* Vtb = (ushort_t*)p; p += T * 2;              // [BH][D][S]

  const float qscale = 0.125f * 1.4426950408889634f;     // 1/sqrt(D) * log2(e)

  cast_x<<<dim3((int)(T / 1024)), dim3(256), 0, stream>>>(x, xb, (int)T);
  transpose_cast<<<dim3(N3 / 32, E / 32), dim3(256), 0, stream>>>(W_attn, Wab, E, N3);
  transpose_cast<<<dim3(E / 32, E / 32), dim3(256), 0, stream>>>(W_proj, Wpb, E, E);
  gemm_bt<2><<<dim3(N3 / 128, M / 128), dim3(256), 0, stream>>>(
      xb, Wab, b_attn, Qb, Kb, Vtb, nullptr, M, N3, E, qscale);
  attn_kernel<<<dim3(1024), dim3(256), 0, stream>>>(Qb, Kb, Vtb, xb);
  gemm_bt<1><<<dim3(E / 128, M / 128), dim3(256), 0, stream>>>(
      xb, Wpb, b_proj, nullptr, nullptr, nullptr, out, M, E, E, 1.0f);
}

// Round 4
// 191.969 us; speedup vs baseline: 1.3287x; 1.1877x over previous
//
#include <hip/hip_runtime.h>
#include <hip/hip_bf16.h>
#include <stdint.h>

typedef unsigned short ushort_t;
typedef __attribute__((ext_vector_type(8))) __bf16 bf16x8;
typedef __attribute__((ext_vector_type(4))) float f32x4;

typedef const __attribute__((address_space(1))) uint32_t* gptr_t;
typedef __attribute__((address_space(3))) uint32_t* lptr_t;

__device__ __forceinline__ ushort_t f2bf(float f) {
  union { float f; uint32_t u; } x; x.f = f;
  uint32_t u = x.u;
  uint32_t r = (u + 0x7fffu + ((u >> 16) & 1u)) >> 16;
  return (ushort_t)r;
}

__device__ __forceinline__ uint32_t cvt_pk_bf16(float lo, float hi) {
  uint32_t r;
  asm("v_cvt_pk_bf16_f32 %0, %1, %2" : "=v"(r) : "v"(lo), "v"(hi));
  return r;
}

__device__ __forceinline__ void gload_lds16(const void* g, void* l) {
  __builtin_amdgcn_global_load_lds((gptr_t)g, (lptr_t)l, 16, 0, 0);
}

// ---------------- cast x (fp32 -> bf16) ----------------
__global__ void cast_x(const float* __restrict__ in, ushort_t* __restrict__ out, int n) {
  const int idx = (blockIdx.x * 256 + threadIdx.x) * 4;
  if (idx < n) {
    const float4 v = *(const float4*)(in + idx);
    ushort4 o;
    o.x = f2bf(v.x); o.y = f2bf(v.y); o.z = f2bf(v.z); o.w = f2bf(v.w);
    *(ushort4*)(out + idx) = o;
  }
}

// ---------------- transpose + cast weights: in[K][N] fp32 -> out[N][K] bf16 ----------------
__global__ void transpose_cast(const float* __restrict__ in, ushort_t* __restrict__ out, int K, int N) {
  __shared__ ushort_t t[32][33];
  const int n0 = blockIdx.x * 32, k0 = blockIdx.y * 32;
  const int c = threadIdx.x & 31, r0 = threadIdx.x >> 5;
#pragma unroll
  for (int i = 0; i < 4; ++i) {
    const int r = r0 + i * 8;
    t[r][c] = f2bf(in[(size_t)(k0 + r) * N + n0 + c]);
  }
  __syncthreads();
#pragma unroll
  for (int i = 0; i < 4; ++i) {
    const int r = r0 + i * 8;
    out[(size_t)(n0 + r) * K + k0 + c] = t[c][r];
  }
}

// ---------------- GEMM: C[M,N] = A[M,K] * Bt[N,K]^T + bias ----------------
// MODE 1: fp32 out to Cf.
// MODE 2: bf16 out scattered: Q,K -> [BH][S][D] (Q pre-scaled), V -> [BH][D][S].
template<int MODE>
__global__ __launch_bounds__(256, 2) void gemm_bt(
    const ushort_t* __restrict__ A, const ushort_t* __restrict__ Bt,
    const float* __restrict__ bias,
    ushort_t* __restrict__ Cq, ushort_t* __restrict__ Ck, ushort_t* __restrict__ Cv,
    float* __restrict__ Cf,
    int M, int N, int K, float qscale)
{
  __shared__ ushort_t As[128 * 64];
  __shared__ ushort_t Bs[128 * 64];
  const int tid = threadIdx.x;
  const int w = tid >> 6, l = tid & 63;
  const int bm = blockIdx.y * 128, bn = blockIdx.x * 128;
  const int lr = l >> 3, lp = l & 7;
  const int l16 = l & 15, lhi = l >> 4;
  const int wm = (w >> 1) * 64, wn = (w & 1) * 64;

  f32x4 acc[4][4] = {};

  for (int kt = 0; kt < K; kt += 64) {
#pragma unroll
    for (int i = 0; i < 4; ++i) {
      const int ci = i * 4 + w;
      const int row = ci * 8 + lr;
      const int sc = (lp ^ (row & 7)) * 8;
      gload_lds16(A + (size_t)(bm + row) * K + kt + sc, &As[ci * 512]);
      gload_lds16(Bt + (size_t)(bn + row) * K + kt + sc, &Bs[ci * 512]);
    }
    __syncthreads();

    bf16x8 af[4][2], bfr[4][2];
#pragma unroll
    for (int mf = 0; mf < 4; ++mf) {
      const int row = wm + mf * 16 + l16;
#pragma unroll
      for (int kf = 0; kf < 2; ++kf) {
        const int ch = (lhi + kf * 4) ^ (row & 7);
        af[mf][kf] = *(const bf16x8*)((const char*)&As[row * 64] + ch * 16);
      }
    }
#pragma unroll
    for (int nf = 0; nf < 4; ++nf) {
      const int row = wn + nf * 16 + l16;
#pragma unroll
      for (int kf = 0; kf < 2; ++kf) {
        const int ch = (lhi + kf * 4) ^ (row & 7);
        bfr[nf][kf] = *(const bf16x8*)((const char*)&Bs[row * 64] + ch * 16);
      }
    }
#pragma unroll
    for (int kf = 0; kf < 2; ++kf)
#pragma unroll
      for (int mf = 0; mf < 4; ++mf)
#pragma unroll
        for (int nf = 0; nf < 4; ++nf)
          acc[mf][nf] = __builtin_amdgcn_mfma_f32_16x16x32_bf16(
              af[mf][kf], bfr[nf][kf], acc[mf][nf], 0, 0, 0);
    __syncthreads();
  }

#pragma unroll
  for (int mf = 0; mf < 4; ++mf) {
#pragma unroll
    for (int nf = 0; nf < 4; ++nf) {
      const int col = bn + wn + nf * 16 + l16;
      const float bv = bias[col];
#pragma unroll
      for (int r = 0; r < 4; ++r) {
        const int row = bm + wm + mf * 16 + lhi * 4 + r;
        float v = acc[mf][nf][r] + bv;
        if constexpr (MODE == 1) {
          Cf[(size_t)row * N + col] = v;
        } else {
          const int region = col >> 10;
          const int hcol = col & 1023;
          const int b_ = row >> 10, s_ = row & 1023;
          const int h_ = hcol >> 6, d_ = hcol & 63;
          if (region == 2) {
            // V: write transposed [BH][D][S]
            Cv[((size_t)(b_ * 16 + h_) * 64 + d_) * 1024 + s_] = f2bf(v);
          } else {
            ushort_t* base = (region == 0) ? Cq : Ck;
            if (region == 0) v *= qscale;
            base[((size_t)(b_ * 16 + h_) * 1024 + s_) * 64 + d_] = f2bf(v);
          }
        }
      }
    }
  }
}

// ---------------- causal flash attention (swapped-operand, paired q-tiles) ----------------
// Q pre-scaled by 0.125*log2(e); Q,K in [BH][S][D]; V in [BH][D][S]; out bf16 [B,S,E].
// Every wave processes 32 q-rows of tile p and 32 q-rows of tile 7-p: per-wave work is
// UNIFORM across the whole grid (16 or 18 half-tiles), so no CU-level load imbalance.
// K/V fragments loaded once per kv-tile, shared by both halves. No __syncthreads.
__global__ __launch_bounds__(256, 2) void attn_kernel(
    const ushort_t* __restrict__ Q, const ushort_t* __restrict__ Kk,
    const ushort_t* __restrict__ Vt, ushort_t* __restrict__ O)
{
  __shared__ ushort_t Pl[8][32 * 68];  // [wave*2+half][q][64 kv + 4 pad] (136 B rows)
  const int tid = threadIdx.x;
  const int w = tid >> 6, l = tid & 63;
  const int l16 = l & 15, lhi = l >> 4;

  // 512 blocks: bid&7 = head&7 -> all 4 pair-blocks of a head on one XCD (K/V L2-resident).
  const int bid = blockIdx.x;
  const int bh = ((bid >> 5) << 3) | (bid & 7);   // head 0..127
  const int p  = (bid >> 3) & 3;                  // pair 0..3
  const int qtH = 7 - p, qtL = p;
  const int qbH = qtH * 128 + w * 32;
  const int qbL = qtL * 128 + w * 32;
  const int ntH = (qbH >> 6) + 1;
  const int ntL = (qbL >> 6) + 1;
  const size_t hb = (size_t)bh * (1024 * 64);
  const int b_ = bh >> 4, h_ = bh & 15;

  // Q fragments (B-operand: lane holds Q[q=l16][ch=kf*32+lhi*8+j])
  bf16x8 qfH[2][2], qfL[2][2];
#pragma unroll
  for (int mf = 0; mf < 2; ++mf)
#pragma unroll
    for (int kf = 0; kf < 2; ++kf) {
      qfH[mf][kf] = *(const bf16x8*)(Q + hb + (size_t)(qbH + mf * 16 + l16) * 64 + kf * 32 + lhi * 8);
      qfL[mf][kf] = *(const bf16x8*)(Q + hb + (size_t)(qbL + mf * 16 + l16) * 64 + kf * 32 + lhi * 8);
    }

  f32x4 oH[2][4] = {}, oL[2][4] = {};
  float mH[2] = {-1e30f, -1e30f}, lsH[2] = {0.0f, 0.0f};
  float mL[2] = {-1e30f, -1e30f}, lsL[2] = {0.0f, 0.0f};
  char* const pbH = (char*)&Pl[w * 2 + 0][0];
  char* const pbL = (char*)&Pl[w * 2 + 1][0];

  for (int t = 0; t < ntH; ++t) {
    const int kv0 = t * 64;

    // K fragments (A-operand: lane holds K[kv=nf*16+l16][ch=kf*32+lhi*8+j]) — shared by halves
    bf16x8 kb[4][2], vb[4][2];
#pragma unroll
    for (int nf = 0; nf < 4; ++nf)
#pragma unroll
      for (int kf = 0; kf < 2; ++kf) {
        kb[nf][kf] = *(const bf16x8*)(Kk + hb + (size_t)(kv0 + nf * 16 + l16) * 64 + kf * 32 + lhi * 8);
        vb[nf][kf] = *(const bf16x8*)(Vt + hb + (size_t)(nf * 16 + l16) * 1024 + kv0 + kf * 32 + lhi * 8);
      }

    auto half = [&](const bf16x8 (&qf)[2][2], f32x4 (&o)[2][4],
                    float (&m_run)[2], float (&l_run)[2],
                    const int qbase, char* const pbase) {
      // S^T[kv][q] = K·Q^T
      f32x4 s[2][4] = {};
#pragma unroll
      for (int nf = 0; nf < 4; ++nf)
#pragma unroll
        for (int kf = 0; kf < 2; ++kf)
#pragma unroll
          for (int mf = 0; mf < 2; ++mf)
            s[mf][nf] = __builtin_amdgcn_mfma_f32_16x16x32_bf16(kb[nf][kf], qf[mf][kf], s[mf][nf], 0, 0, 0);

      if (kv0 + 63 > qbase) {  // diagonal tile: elementwise causal mask
#pragma unroll
        for (int mf = 0; mf < 2; ++mf) {
          const int q = qbase + mf * 16 + l16;
#pragma unroll
          for (int nf = 0; nf < 4; ++nf)
#pragma unroll
            for (int r = 0; r < 4; ++r) {
              const int kv = kv0 + nf * 16 + lhi * 4 + r;
              if (kv > q) s[mf][nf][r] = -1e30f;
            }
        }
      }

      // online softmax: in-register over 16 kv + 2 shfl_xor across lhi partners
#pragma unroll
      for (int mf = 0; mf < 2; ++mf) {
        float lmax = -1e30f;
#pragma unroll
        for (int nf = 0; nf < 4; ++nf)
#pragma unroll
          for (int r = 0; r < 4; ++r) lmax = fmaxf(lmax, s[mf][nf][r]);
        lmax = fmaxf(lmax, __shfl_xor(lmax, 16));
        lmax = fmaxf(lmax, __shfl_xor(lmax, 32));
        const float mnew = fmaxf(m_run[mf], lmax);
        const float corr = exp2f(m_run[mf] - mnew);
        float psum = 0.0f;
#pragma unroll
        for (int nf = 0; nf < 4; ++nf)
#pragma unroll
          for (int r = 0; r < 4; ++r) {
            const float pv = exp2f(s[mf][nf][r] - mnew);
            s[mf][nf][r] = pv;
            psum += pv;
          }
        psum += __shfl_xor(psum, 16);
        psum += __shfl_xor(psum, 32);
        l_run[mf] = l_run[mf] * corr + psum;
        m_run[mf] = mnew;
#pragma unroll
        for (int nf = 0; nf < 4; ++nf) o[mf][nf] *= corr;

        // store P row q (bf16): P[q][kv = nf*16+lhi*4 + 0..3], padded rows (no XOR)
        const int q = mf * 16 + l16;
#pragma unroll
        for (int nf = 0; nf < 4; ++nf) {
          const uint32_t u0 = cvt_pk_bf16(s[mf][nf][0], s[mf][nf][1]);
          const uint32_t u1 = cvt_pk_bf16(s[mf][nf][2], s[mf][nf][3]);
          *(uint2*)(pbase + q * 136 + nf * 32 + lhi * 8) = make_uint2(u0, u1);
        }
      }

      // O^T += V^T·P^T  (wave-private LDS, compiler inserts lgkmcnt wait)
#pragma unroll
      for (int mf = 0; mf < 2; ++mf) {
        const int q = mf * 16 + l16;
#pragma unroll
        for (int kf = 0; kf < 2; ++kf) {
          const bf16x8 pb = *(const bf16x8*)(pbase + q * 136 + kf * 64 + lhi * 16);
#pragma unroll
          for (int nf = 0; nf < 4; ++nf)
            o[mf][nf] = __builtin_amdgcn_mfma_f32_16x16x32_bf16(vb[nf][kf], pb, o[mf][nf], 0, 0, 0);
        }
      }
    };

    half(qfH, oH, mH, lsH, qbH, pbH);
    if (t < ntL) half(qfL, oL, mL, lsL, qbL, pbL);
  }

  // epilogue: normalize, pack 4 bf16 (consecutive d) per store
  auto epi = [&](f32x4 (&o)[2][4], float (&l_run)[2], const int qbase) {
#pragma unroll
    for (int mf = 0; mf < 2; ++mf) {
      const float inv = 1.0f / l_run[mf];
      const int qrow = qbase + mf * 16 + l16;
      const size_t rb = ((size_t)(b_ * 1024 + qrow)) * 1024 + h_ * 64;
#pragma unroll
      for (int nf = 0; nf < 4; ++nf) {
        const uint32_t u0 = cvt_pk_bf16(o[mf][nf][0] * inv, o[mf][nf][1] * inv);
        const uint32_t u1 = cvt_pk_bf16(o[mf][nf][2] * inv, o[mf][nf][3] * inv);
        *(uint2*)(O + rb + nf * 16 + lhi * 4) = make_uint2(u0, u1);
      }
    }
  };
  epi(oH, lsH, qbH);
  epi(oL, lsL, qbL);
}

extern "C" void kernel_launch(void* const* d_in, const int* in_sizes, int n_in,
                              void* d_out, int out_size, void* d_ws, size_t ws_size,
                              hipStream_t stream) {
  const float* x      = (const float*)d_in[0];
  const float* W_attn = (const float*)d_in[1];
  const float* b_attn = (const float*)d_in[2];
  const float* W_proj = (const float*)d_in[3];
  const float* b_proj = (const float*)d_in[4];
  float* out = (float*)d_out;

  const int M = 8192;       // B*S
  const int E = 1024, N3 = 3072;
  const size_t T = (size_t)M * E;  // 8.4M elements per [B,S,E]-sized bf16 tensor

  char* p = (char*)d_ws;
  ushort_t* xb  = (ushort_t*)p; p += T * 2;              // x bf16; reused as attn_out
  ushort_t* Wab = (ushort_t*)p; p += (size_t)N3 * E * 2; // W_attn^T bf16 [3072][1024]
  ushort_t* Wpb = (ushort_t*)p; p += (size_t)E * E * 2;  // W_proj^T bf16 [1024][1024]
  ushort_t* Qb  = (ushort_t*)p; p += T * 2;              // [BH][S][D]
  ushort_t* Kb  = (ushort_t*)p; p += T * 2;              // [BH][S][D]
  ushort_t* Vtb = (ushort_t*)p; p += T * 2;              // [BH][D][S]

  const float qscale = 0.125f * 1.4426950408889634f;     // 1/sqrt(D) * log2(e)

  cast_x<<<dim3((int)(T / 1024)), dim3(256), 0, stream>>>(x, xb, (int)T);
  transpose_cast<<<dim3(N3 / 32, E / 32), dim3(256), 0, stream>>>(W_attn, Wab, E, N3);
  transpose_cast<<<dim3(E / 32, E / 32), dim3(256), 0, stream>>>(W_proj, Wpb, E, E);
  gemm_bt<2><<<dim3(N3 / 128, M / 128), dim3(256), 0, stream>>>(
      xb, Wab, b_attn, Qb, Kb, Vtb, nullptr, M, N3, E, qscale);
  attn_kernel<<<dim3(512), dim3(256), 0, stream>>>(Qb, Kb, Vtb, xb);
  gemm_bt<1><<<dim3(E / 128, M / 128), dim3(256), 0, stream>>>(
      xb, Wpb, b_proj, nullptr, nullptr, nullptr, out, M, E, E, 1.0f);
}